// Round 3
// baseline (483.286 us; speedup 1.0000x reference)
//
#include <hip/hip_runtime.h>

typedef unsigned short u16;
typedef float f32x4 __attribute__((ext_vector_type(4)));
typedef __bf16 bf16x8 __attribute__((ext_vector_type(8)));

#define T_ 4096
#define D_ 1024
#define NW_ 64

__device__ __forceinline__ float b2f(u16 u) {
  return __uint_as_float(((unsigned)u) << 16);
}
__device__ __forceinline__ u16 f2bf(float f) {
  unsigned u = __float_as_uint(f);
  u += 0x7fffu + ((u >> 16) & 1u);   // RNE
  return (u16)(u >> 16);
}

// fp32 -> bf16 cast, 4 elements/thread. n % 4 == 0.
__global__ __launch_bounds__(256) void cvt_k(const float* __restrict__ src,
                                             u16* __restrict__ dst, long n)
{
  long i = ((long)blockIdx.x * 256 + threadIdx.x) * 4;
  if (i >= n) return;
  float4 v = *(const float4*)(src + i);
  ushort4 o;
  o.x = f2bf(v.x); o.y = f2bf(v.y); o.z = f2bf(v.z); o.w = f2bf(v.w);
  *(ushort4*)(dst + i) = o;
}

// C(M,N) = A(M,K;lda) @ B(N,K)^T [+ bias], A/B bf16, fp32 accum.
// Output: fp32 to C32 if non-null, else bf16 to C16. M,N,K % 128 == 0.
__global__ __launch_bounds__(256) void gemm_bt(
    const u16* __restrict__ A, const u16* __restrict__ Bm,
    u16* __restrict__ C16, float* __restrict__ C32,
    const float* __restrict__ bias, int M, int N, int K, int lda)
{
  __shared__ u16 As[128 * 32];
  __shared__ u16 Bs[128 * 32];
  const int tid = threadIdx.x;
  const int lane = tid & 63;
  const int w = tid >> 6;
  const int wm = w >> 1, wn = w & 1;
  const int q = lane >> 4, il = lane & 15;
  const long m0 = (long)blockIdx.y * 128, n0 = (long)blockIdx.x * 128;
  const int r0 = tid >> 2, kp = tid & 3;   // (row, k-part) for staging

  f32x4 acc[4][4] = {};

  for (int k0 = 0; k0 < K; k0 += 32) {
    uint4 a0 = *(const uint4*)(A + (m0 + r0) * (long)lda + k0 + kp * 8);
    uint4 a1 = *(const uint4*)(A + (m0 + r0 + 64) * (long)lda + k0 + kp * 8);
    uint4 b0 = *(const uint4*)(Bm + (n0 + r0) * (long)K + k0 + kp * 8);
    uint4 b1 = *(const uint4*)(Bm + (n0 + r0 + 64) * (long)K + k0 + kp * 8);
    __syncthreads();   // prior iteration's fragment reads complete
    *(uint4*)&As[r0 * 32 + kp * 8] = a0;
    *(uint4*)&As[(r0 + 64) * 32 + kp * 8] = a1;
    *(uint4*)&Bs[r0 * 32 + kp * 8] = b0;
    *(uint4*)&Bs[(r0 + 64) * 32 + kp * 8] = b1;
    __syncthreads();

    bf16x8 af[4], bfr[4];
#pragma unroll
    for (int mt = 0; mt < 4; ++mt)
      af[mt] = *(const bf16x8*)&As[(wm * 64 + mt * 16 + il) * 32 + q * 8];
#pragma unroll
    for (int nt = 0; nt < 4; ++nt)
      bfr[nt] = *(const bf16x8*)&Bs[(wn * 64 + nt * 16 + il) * 32 + q * 8];
#pragma unroll
    for (int mt = 0; mt < 4; ++mt)
#pragma unroll
      for (int nt = 0; nt < 4; ++nt)
        acc[mt][nt] = __builtin_amdgcn_mfma_f32_16x16x32_bf16(af[mt], bfr[nt], acc[mt][nt], 0, 0, 0);
  }

#pragma unroll
  for (int nt = 0; nt < 4; ++nt) {
    const long col = n0 + wn * 64 + nt * 16 + il;
    const float bv = bias ? bias[col] : 0.0f;
#pragma unroll
    for (int mt = 0; mt < 4; ++mt) {
#pragma unroll
      for (int r = 0; r < 4; ++r) {
        const long row = m0 + wm * 64 + mt * 16 + q * 4 + r;
        const float v = acc[mt][nt][r] + bv;
        if (C32) C32[row * N + col] = v;
        else     C16[row * N + col] = f2bf(v);
      }
    }
  }
}

// scores[r] = mean(tanh(y[r, :])) over D=1024 (y bf16, bias already added)
__global__ __launch_bounds__(256) void scores_k(const u16* __restrict__ y,
                                                float* __restrict__ scores)
{
  const int lane = threadIdx.x & 63;
  const long r = (long)blockIdx.x * 4 + (threadIdx.x >> 6);
  const u16* p = y + r * D_ + lane * 16;
  uint4 v0 = *(const uint4*)p;
  uint4 v1 = *(const uint4*)(p + 8);
  union { uint4 v; u16 s[8]; } a, c;
  a.v = v0; c.v = v1;
  float s = 0.f;
#pragma unroll
  for (int e = 0; e < 8; ++e) s += tanhf(b2f(a.s[e]));
#pragma unroll
  for (int e = 0; e < 8; ++e) s += tanhf(b2f(c.s[e]));
#pragma unroll
  for (int o = 32; o; o >>= 1) s += __shfl_xor(s, o, 64);
  if (lane == 0) scores[r] = s * (1.0f / 1024.0f);
}

// per-window softmax over scores -> weighted sum of fp32 x rows -> summaries
__global__ __launch_bounds__(256) void summar_k(const float* __restrict__ x,
                                                const float* __restrict__ scores,
                                                float* __restrict__ summ)
{
  __shared__ float wts[64];
  const int tid = threadIdx.x;
  const int b = blockIdx.x >> 6, n = blockIdx.x & 63;
  if (tid < 64) {
    float v = scores[(long)b * T_ + n * 64 + tid];
    float mx = v;
#pragma unroll
    for (int o = 32; o; o >>= 1) mx = fmaxf(mx, __shfl_xor(mx, o, 64));
    float e = __expf(v - mx);
    float s = e;
#pragma unroll
    for (int o = 32; o; o >>= 1) s += __shfl_xor(s, o, 64);
    wts[tid] = e / s;
  }
  __syncthreads();
  const int d0 = tid * 4;
  const float* xp = x + ((long)b * T_ + n * 64) * D_ + d0;
  float a0 = 0, a1 = 0, a2 = 0, a3 = 0;
  for (int wd = 0; wd < 64; ++wd) {
    float4 v = *(const float4*)(xp + (long)wd * D_);
    float wv = wts[wd];
    a0 += wv * v.x; a1 += wv * v.y; a2 += wv * v.z; a3 += wv * v.w;
  }
  *(float4*)(summ + ((long)b * NW_ + n) * D_ + d0) = make_float4(a0, a1, a2, a3);
}

// cross-summary attention: cs_out[b,n,:] = softmax(summ[n]·jit[m]/32)_m @ jit
__global__ __launch_bounds__(256) void cross_k(const float* __restrict__ summ,
                                               const int* __restrict__ jitter,
                                               float* __restrict__ cso)
{
  __shared__ float sm[64], pm[64];
  __shared__ int jidx[64];
  const int tid = threadIdx.x;
  const int b = blockIdx.x >> 6, n = blockIdx.x & 63;
  if (tid < 64) jidx[tid] = jitter[tid];
  __syncthreads();
  const int m = tid >> 2, part = tid & 3;
  const float* sn = summ + ((long)b * NW_ + n) * D_;
  const float* sj = summ + ((long)b * NW_ + jidx[m]) * D_;
  float p = 0.f;
  for (int d = part * 256; d < part * 256 + 256; d += 4) {
    float4 aa = *(const float4*)(sn + d);
    float4 bb = *(const float4*)(sj + d);
    p += aa.x * bb.x + aa.y * bb.y + aa.z * bb.z + aa.w * bb.w;
  }
  p += __shfl_xor(p, 1, 64);
  p += __shfl_xor(p, 2, 64);
  if (part == 0) sm[m] = p * (1.0f / 32.0f);
  __syncthreads();
  if (tid < 64) {
    float v = sm[tid], mx = v;
#pragma unroll
    for (int o = 32; o; o >>= 1) mx = fmaxf(mx, __shfl_xor(mx, o, 64));
    float e = __expf(v - mx), s = e;
#pragma unroll
    for (int o = 32; o; o >>= 1) s += __shfl_xor(s, o, 64);
    pm[tid] = e / s;
  }
  __syncthreads();
  const int d0 = tid * 4;
  float a0 = 0, a1 = 0, a2 = 0, a3 = 0;
  for (int mm = 0; mm < 64; ++mm) {
    const float* sr = summ + ((long)b * NW_ + jidx[mm]) * D_ + d0;
    float wv = pm[mm];
    float4 vv = *(const float4*)sr;
    a0 += wv * vv.x; a1 += wv * vv.y; a2 += wv * vv.z; a3 += wv * vv.w;
  }
  *(float4*)(cso + ((long)b * NW_ + n) * D_ + d0) = make_float4(a0, a1, a2, a3);
}

// windowed attention, one block per (b,h,n); writes final = local + 0.25*cs
// IN-PLACE into the q-slice (cols [0,1024)) of qkv: each block writes only
// the (rows, head-cols) region that only it reads (before its barrier).
__global__ __launch_bounds__(256) void attn_win(u16* qkv,
                                                const float* __restrict__ cso)
{
  __shared__ u16 Qs[64 * 72], Ks[64 * 72], Vt[64 * 72], Ps[64 * 72];
  const int tid = threadIdx.x;
  const int lane = tid & 63;
  const int w = tid >> 6;
  const int q = lane >> 4, il = lane & 15;
  const int bid = blockIdx.x;
  const int n = bid & 63;
  const int h = (bid >> 6) & 15;
  const int b = bid >> 10;
  const long rowbase = (long)b * T_ + n * 64;

#pragma unroll
  for (int i = 0; i < 2; ++i) {
    int u = i * 256 + tid;
    int row = u >> 3, cp = u & 7;
    const u16* src = qkv + (rowbase + row) * 3072 + h * 64 + cp * 8;
    uint4 qv = *(const uint4*)src;
    uint4 kv = *(const uint4*)(src + 1024);
    uint4 vv = *(const uint4*)(src + 2048);
    *(uint4*)&Qs[row * 72 + cp * 8] = qv;
    *(uint4*)&Ks[row * 72 + cp * 8] = kv;
    union { uint4 v; u16 s[8]; } uv; uv.v = vv;
#pragma unroll
    for (int e = 0; e < 8; ++e)
      Vt[(cp * 8 + e) * 72 + row] = uv.s[e];   // transposed for PV B-operand
  }
  __syncthreads();

  // S = Q K^T : wave w owns rows [16w,16w+16), 4 col-tiles of 16
  f32x4 sacc[4] = {};
#pragma unroll
  for (int ks = 0; ks < 2; ++ks) {
    bf16x8 aq = *(const bf16x8*)&Qs[(w * 16 + il) * 72 + ks * 32 + q * 8];
#pragma unroll
    for (int ct = 0; ct < 4; ++ct) {
      bf16x8 bk = *(const bf16x8*)&Ks[(ct * 16 + il) * 72 + ks * 32 + q * 8];
      sacc[ct] = __builtin_amdgcn_mfma_f32_16x16x32_bf16(aq, bk, sacc[ct], 0, 0, 0);
    }
  }

  // row softmax: row = 16w+4q+r; its 64 cols live in lanes [16q,16q+16) x 4 tiles
#pragma unroll
  for (int r = 0; r < 4; ++r) {
    float s0 = sacc[0][r] * 0.125f, s1 = sacc[1][r] * 0.125f,
          s2 = sacc[2][r] * 0.125f, s3 = sacc[3][r] * 0.125f;
    float mx = fmaxf(fmaxf(s0, s1), fmaxf(s2, s3));
#pragma unroll
    for (int o = 1; o < 16; o <<= 1) mx = fmaxf(mx, __shfl_xor(mx, o, 64));
    float e0 = __expf(s0 - mx), e1 = __expf(s1 - mx),
          e2 = __expf(s2 - mx), e3 = __expf(s3 - mx);
    float sum = e0 + e1 + e2 + e3;
#pragma unroll
    for (int o = 1; o < 16; o <<= 1) sum += __shfl_xor(sum, o, 64);
    float inv = 1.0f / sum;
    int prow = w * 16 + q * 4 + r;
    Ps[prow * 72 + 0 * 16 + il] = f2bf(e0 * inv);
    Ps[prow * 72 + 1 * 16 + il] = f2bf(e1 * inv);
    Ps[prow * 72 + 2 * 16 + il] = f2bf(e2 * inv);
    Ps[prow * 72 + 3 * 16 + il] = f2bf(e3 * inv);
  }
  __syncthreads();

  // O = P V : A-frag from Ps rows, B-frag from Vt rows (= V columns)
  f32x4 oacc[4] = {};
#pragma unroll
  for (int ks = 0; ks < 2; ++ks) {
    bf16x8 ap = *(const bf16x8*)&Ps[(w * 16 + il) * 72 + ks * 32 + q * 8];
#pragma unroll
    for (int dt = 0; dt < 4; ++dt) {
      bf16x8 bv = *(const bf16x8*)&Vt[(dt * 16 + il) * 72 + ks * 32 + q * 8];
      oacc[dt] = __builtin_amdgcn_mfma_f32_16x16x32_bf16(ap, bv, oacc[dt], 0, 0, 0);
    }
  }

  const float* cs = cso + ((long)b * NW_ + n) * D_ + h * 64;
#pragma unroll
  for (int dt = 0; dt < 4; ++dt) {
    int col = dt * 16 + il;
    float cadd = 0.25f * cs[col];
#pragma unroll
    for (int r = 0; r < 4; ++r) {
      int row = w * 16 + q * 4 + r;
      qkv[(rowbase + row) * 3072 + h * 64 + col] = f2bf(oacc[dt][r] + cadd);
    }
  }
}

extern "C" void kernel_launch(void* const* d_in, const int* in_sizes, int n_in,
                              void* d_out, int out_size, void* d_ws, size_t ws_size,
                              hipStream_t stream)
{
  (void)in_sizes; (void)n_in; (void)out_size; (void)ws_size;
  const float* x      = (const float*)d_in[0];
  const float* Wqkv   = (const float*)d_in[1];
  const float* Wout   = (const float*)d_in[2];
  const float* bout   = (const float*)d_in[3];
  const float* Wcross = (const float*)d_in[4];
  const float* bcross = (const float*)d_in[5];
  const int*   jitter = (const int*)d_in[6];
  float* out = (float*)d_out;

  // ws layout (bytes), total 144,769,024:
  //   qkv    @ 0           : 16384x3072 bf16 = 100,663,296  (y bf16 aliases @0)
  //   xb     @ 100,663,296 : 16384x1024 bf16 =  33,554,432
  //   wqkvb  @ 134,217,728 : 3072x1024 bf16  =   6,291,456
  //   wtmp   @ 140,509,184 : 1024x1024 bf16  =   2,097,152  (Wcross, then Wout)
  //   scores @ 142,606,336 : 16384 f32       =      65,536
  //   summ   @ 142,671,872 : 4x64x1024 f32   =   1,048,576
  //   cso    @ 143,720,448 : 4x64x1024 f32   =   1,048,576
  char* ws = (char*)d_ws;
  u16*   qkv    = (u16*)ws;
  u16*   y      = (u16*)ws;                      // dead before qkv GEMM
  u16*   xb     = (u16*)(ws + 100663296);
  u16*   wqkvb  = (u16*)(ws + 134217728);
  u16*   wtmp   = (u16*)(ws + 140509184);
  float* scores = (float*)(ws + 142606336);
  float* summ   = (float*)(ws + 142671872);
  float* cso    = (float*)(ws + 143720448);

  dim3 blk(256);
  // input casts
  cvt_k<<<16384, blk, 0, stream>>>(x, xb, 16777216L);
  cvt_k<<<1024, blk, 0, stream>>>(Wcross, wtmp, 1048576L);
  // cross-score path
  gemm_bt<<<dim3(8, 128), blk, 0, stream>>>(xb, wtmp, y, nullptr, bcross, 16384, 1024, 1024, 1024);
  scores_k<<<4096, blk, 0, stream>>>(y, scores);
  summar_k<<<256, blk, 0, stream>>>(x, scores, summ);
  cross_k<<<256, blk, 0, stream>>>(summ, jitter, cso);
  // main path (y dead now; qkv overwrites it)
  cvt_k<<<3072, blk, 0, stream>>>(Wqkv, wqkvb, 3145728L);
  gemm_bt<<<dim3(24, 128), blk, 0, stream>>>(xb, wqkvb, qkv, nullptr, nullptr, 16384, 3072, 1024, 1024);
  attn_win<<<4096, blk, 0, stream>>>(qkv, cso);   // in-place -> q-slice
  cvt_k<<<1024, blk, 0, stream>>>(Wout, wtmp, 1048576L);
  gemm_bt<<<dim3(8, 128), blk, 0, stream>>>(qkv, wtmp, nullptr, out, bout, 16384, 1024, 1024, 3072);
}

// Round 4
// 481.523 us; speedup vs baseline: 1.0037x; 1.0037x over previous
//
#include <hip/hip_runtime.h>

typedef unsigned short u16;
typedef float f32x4 __attribute__((ext_vector_type(4)));
typedef __bf16 bf16x8 __attribute__((ext_vector_type(8)));

#define T_ 4096
#define D_ 1024
#define NW_ 64

__device__ __forceinline__ float b2f(u16 u) {
  return __uint_as_float(((unsigned)u) << 16);
}
__device__ __forceinline__ u16 f2bf(float f) {
  unsigned u = __float_as_uint(f);
  u += 0x7fffu + ((u >> 16) & 1u);   // RNE
  return (u16)(u >> 16);
}
__device__ __forceinline__ void g2l16(const u16* g, u16* l) {
  __builtin_amdgcn_global_load_lds((const __attribute__((address_space(1))) void*)g,
                                   (__attribute__((address_space(3))) void*)l, 16, 0, 0);
}

// fused fp32->bf16 casts: x (16384 blk), Wqkv (3072 blk), Wcross (1024 blk)
__global__ __launch_bounds__(256) void cvt3_k(const float* __restrict__ s0, u16* __restrict__ d0,
                                              const float* __restrict__ s1, u16* __restrict__ d1,
                                              const float* __restrict__ s2, u16* __restrict__ d2)
{
  long bid = blockIdx.x;
  const float* src; u16* dst; long base;
  if (bid < 16384)      { src = s0; dst = d0; base = bid * 1024; }
  else if (bid < 19456) { src = s1; dst = d1; base = (bid - 16384) * 1024; }
  else                  { src = s2; dst = d2; base = (bid - 19456) * 1024; }
  long i = base + (long)threadIdx.x * 4;
  float4 v = *(const float4*)(src + i);
  ushort4 o;
  o.x = f2bf(v.x); o.y = f2bf(v.y); o.z = f2bf(v.z); o.w = f2bf(v.w);
  *(ushort4*)(dst + i) = o;
}

__global__ __launch_bounds__(256) void cvt_k(const float* __restrict__ src,
                                             u16* __restrict__ dst, long n)
{
  long i = ((long)blockIdx.x * 256 + threadIdx.x) * 4;
  if (i >= n) return;
  float4 v = *(const float4*)(src + i);
  ushort4 o;
  o.x = f2bf(v.x); o.y = f2bf(v.y); o.z = f2bf(v.z); o.w = f2bf(v.w);
  *(ushort4*)(dst + i) = o;
}

// C(M,N) = A(M,K;lda) @ B(N,K)^T [+ bias], A/B bf16, fp32 accum.
// Output: fp32 to C32 if non-null, else bf16 to C16. M,N,K % 128 == 0.
// m97 structure: 128x128 tile, BK=32, global_load_lds width=16 staging.
__global__ __launch_bounds__(256) void gemm_bt(
    const u16* __restrict__ A, const u16* __restrict__ Bm,
    u16* __restrict__ C16, float* __restrict__ C32,
    const float* __restrict__ bias, int M, int N, int K, int lda)
{
  __shared__ u16 As[128 * 32];
  __shared__ u16 Bs[128 * 32];
  const int tid = threadIdx.x;
  const int lane = tid & 63;
  const int w = tid >> 6;
  const int wm = w >> 1, wn = w & 1;
  const int q = lane >> 4, il = lane & 15;
  const long m0 = (long)blockIdx.y * 128, n0 = (long)blockIdx.x * 128;
  const int ua = w * 128 + lane;           // staging unit index

  f32x4 acc[4][4] = {};

  for (int k0 = 0; k0 < K; k0 += 32) {
    // async global -> LDS, 16B/lane, wave-contiguous dst (no padding allowed)
#pragma unroll
    for (int i = 0; i < 2; ++i) {
      int u = ua + i * 64;
      int row = u >> 2, kp = u & 3;
      g2l16(A + (m0 + row) * (long)lda + k0 + kp * 8, &As[(w * 128 + i * 64) * 8]);
      g2l16(Bm + (n0 + row) * (long)K + k0 + kp * 8, &Bs[(w * 128 + i * 64) * 8]);
    }
    __syncthreads();   // drains vmcnt(0): staged tile visible

    bf16x8 af[4], bfr[4];
#pragma unroll
    for (int mt = 0; mt < 4; ++mt)
      af[mt] = *(const bf16x8*)&As[(wm * 64 + mt * 16 + il) * 32 + q * 8];
#pragma unroll
    for (int nt = 0; nt < 4; ++nt)
      bfr[nt] = *(const bf16x8*)&Bs[(wn * 64 + nt * 16 + il) * 32 + q * 8];
#pragma unroll
    for (int mt = 0; mt < 4; ++mt)
#pragma unroll
      for (int nt = 0; nt < 4; ++nt)
        acc[mt][nt] = __builtin_amdgcn_mfma_f32_16x16x32_bf16(af[mt], bfr[nt], acc[mt][nt], 0, 0, 0);
    __syncthreads();   // all frag reads done before next tile's stores land
  }

#pragma unroll
  for (int nt = 0; nt < 4; ++nt) {
    const long col = n0 + wn * 64 + nt * 16 + il;
    const float bv = bias ? bias[col] : 0.0f;
#pragma unroll
    for (int mt = 0; mt < 4; ++mt) {
#pragma unroll
      for (int r = 0; r < 4; ++r) {
        const long row = m0 + wm * 64 + mt * 16 + q * 4 + r;
        const float v = acc[mt][nt][r] + bv;
        if (C32) C32[row * N + col] = v;
        else     C16[row * N + col] = f2bf(v);
      }
    }
  }
}

// scores[r] = mean(tanh(y[r, :])) over D=1024 (y bf16, bias already added)
__global__ __launch_bounds__(256) void scores_k(const u16* __restrict__ y,
                                                float* __restrict__ scores)
{
  const int lane = threadIdx.x & 63;
  const long r = (long)blockIdx.x * 4 + (threadIdx.x >> 6);
  const u16* p = y + r * D_ + lane * 16;
  uint4 v0 = *(const uint4*)p;
  uint4 v1 = *(const uint4*)(p + 8);
  union { uint4 v; u16 s[8]; } a, c;
  a.v = v0; c.v = v1;
  float s = 0.f;
#pragma unroll
  for (int e = 0; e < 8; ++e) s += tanhf(b2f(a.s[e]));
#pragma unroll
  for (int e = 0; e < 8; ++e) s += tanhf(b2f(c.s[e]));
#pragma unroll
  for (int o = 32; o; o >>= 1) s += __shfl_xor(s, o, 64);
  if (lane == 0) scores[r] = s * (1.0f / 1024.0f);
}

// per-window softmax over scores -> weighted sum of fp32 x rows -> summaries
__global__ __launch_bounds__(256) void summar_k(const float* __restrict__ x,
                                                const float* __restrict__ scores,
                                                float* __restrict__ summ)
{
  __shared__ float wts[64];
  const int tid = threadIdx.x;
  const int b = blockIdx.x >> 6, n = blockIdx.x & 63;
  if (tid < 64) {
    float v = scores[(long)b * T_ + n * 64 + tid];
    float mx = v;
#pragma unroll
    for (int o = 32; o; o >>= 1) mx = fmaxf(mx, __shfl_xor(mx, o, 64));
    float e = __expf(v - mx);
    float s = e;
#pragma unroll
    for (int o = 32; o; o >>= 1) s += __shfl_xor(s, o, 64);
    wts[tid] = e / s;
  }
  __syncthreads();
  const int d0 = tid * 4;
  const float* xp = x + ((long)b * T_ + n * 64) * D_ + d0;
  float a0 = 0, a1 = 0, a2 = 0, a3 = 0;
#pragma unroll 4
  for (int wd = 0; wd < 64; ++wd) {
    float4 v = *(const float4*)(xp + (long)wd * D_);
    float wv = wts[wd];
    a0 += wv * v.x; a1 += wv * v.y; a2 += wv * v.z; a3 += wv * v.w;
  }
  *(float4*)(summ + ((long)b * NW_ + n) * D_ + d0) = make_float4(a0, a1, a2, a3);
}

// cross-summary attention: cs_out[b,n,:] = softmax(summ[n]·jit[m]/32)_m @ jit
__global__ __launch_bounds__(256) void cross_k(const float* __restrict__ summ,
                                               const int* __restrict__ jitter,
                                               float* __restrict__ cso)
{
  __shared__ float sm[64], pm[64];
  __shared__ int jidx[64];
  const int tid = threadIdx.x;
  const int b = blockIdx.x >> 6, n = blockIdx.x & 63;
  if (tid < 64) jidx[tid] = jitter[tid];
  __syncthreads();
  const int m = tid >> 2, part = tid & 3;
  const float* sn = summ + ((long)b * NW_ + n) * D_;
  const float* sj = summ + ((long)b * NW_ + jidx[m]) * D_;
  float p = 0.f;
  for (int d = part * 256; d < part * 256 + 256; d += 4) {
    float4 aa = *(const float4*)(sn + d);
    float4 bb = *(const float4*)(sj + d);
    p += aa.x * bb.x + aa.y * bb.y + aa.z * bb.z + aa.w * bb.w;
  }
  p += __shfl_xor(p, 1, 64);
  p += __shfl_xor(p, 2, 64);
  if (part == 0) sm[m] = p * (1.0f / 32.0f);
  __syncthreads();
  if (tid < 64) {
    float v = sm[tid], mx = v;
#pragma unroll
    for (int o = 32; o; o >>= 1) mx = fmaxf(mx, __shfl_xor(mx, o, 64));
    float e = __expf(v - mx), s = e;
#pragma unroll
    for (int o = 32; o; o >>= 1) s += __shfl_xor(s, o, 64);
    pm[tid] = e / s;
  }
  __syncthreads();
  const int d0 = tid * 4;
  float a0 = 0, a1 = 0, a2 = 0, a3 = 0;
  for (int mm = 0; mm < 64; ++mm) {
    const float* sr = summ + ((long)b * NW_ + jidx[mm]) * D_ + d0;
    float wv = pm[mm];
    float4 vv = *(const float4*)sr;
    a0 += wv * vv.x; a1 += wv * vv.y; a2 += wv * vv.z; a3 += wv * vv.w;
  }
  *(float4*)(cso + ((long)b * NW_ + n) * D_ + d0) = make_float4(a0, a1, a2, a3);
}

// windowed attention, one block per (b,h,n); writes final = local + 0.25*cs
// IN-PLACE into the q-slice of qkv (each block writes only the region it reads).
__global__ __launch_bounds__(256) void attn_win(u16* qkv,
                                                const float* __restrict__ cso)
{
  __shared__ u16 Qs[64 * 72], Ks[64 * 72], Vt[64 * 72], Ps[64 * 72];
  unsigned* Vt32 = (unsigned*)Vt;          // word stride 36/row (byte 144, b128-aligned)
  const int tid = threadIdx.x;
  const int lane = tid & 63;
  const int w = tid >> 6;
  const int q = lane >> 4, il = lane & 15;
  const int bid = blockIdx.x;
  const int n = bid & 63;
  const int h = (bid >> 6) & 15;
  const int b = bid >> 10;
  const long rowbase = (long)b * T_ + n * 64;

#pragma unroll
  for (int i = 0; i < 2; ++i) {
    int u = i * 256 + tid;
    int row = u >> 3, cp = u & 7;
    const u16* src = qkv + (rowbase + row) * 3072 + h * 64 + cp * 8;
    uint4 qv = *(const uint4*)src;
    uint4 kv = *(const uint4*)(src + 1024);
    uint4 vv = *(const uint4*)(src + 2048);
    *(uint4*)&Qs[row * 72 + cp * 8] = qv;
    *(uint4*)&Ks[row * 72 + cp * 8] = kv;
    // V transpose via row-pair packing: tid/tid^8 hold rows 2p,2p+1 (same cols).
    union { uint4 v; unsigned u[4]; } mine, part;
    mine.v = vv;
#pragma unroll
    for (int m = 0; m < 4; ++m) part.u[m] = __shfl_xor(mine.u[m], 8, 64);
    const bool even = ((row & 1) == 0);
    const int p = row >> 1;
#pragma unroll
    for (int m = 0; m < 4; ++m) {
      unsigned word = even ? ((mine.u[m] & 0xffffu) | (part.u[m] << 16))
                           : ((part.u[m] >> 16)     | (mine.u[m] & 0xffff0000u));
      int c = cp * 8 + 2 * m + (even ? 0 : 1);     // Vt row = V column
      Vt32[c * 36 + p] = word;                     // u32 store: 4 stores vs 8, ~8-way
    }
  }
  __syncthreads();

  // S = Q K^T : wave w owns rows [16w,16w+16), 4 col-tiles of 16
  f32x4 sacc[4] = {};
#pragma unroll
  for (int ks = 0; ks < 2; ++ks) {
    bf16x8 aq = *(const bf16x8*)&Qs[(w * 16 + il) * 72 + ks * 32 + q * 8];
#pragma unroll
    for (int ct = 0; ct < 4; ++ct) {
      bf16x8 bk = *(const bf16x8*)&Ks[(ct * 16 + il) * 72 + ks * 32 + q * 8];
      sacc[ct] = __builtin_amdgcn_mfma_f32_16x16x32_bf16(aq, bk, sacc[ct], 0, 0, 0);
    }
  }

  // row softmax: row = 16w+4q+r; its 64 cols live in this quad (16 il x 4 tiles)
#pragma unroll
  for (int r = 0; r < 4; ++r) {
    float s0 = sacc[0][r] * 0.125f, s1 = sacc[1][r] * 0.125f,
          s2 = sacc[2][r] * 0.125f, s3 = sacc[3][r] * 0.125f;
    float mx = fmaxf(fmaxf(s0, s1), fmaxf(s2, s3));
#pragma unroll
    for (int o = 1; o < 16; o <<= 1) mx = fmaxf(mx, __shfl_xor(mx, o, 64));
    float e0 = __expf(s0 - mx), e1 = __expf(s1 - mx),
          e2 = __expf(s2 - mx), e3 = __expf(s3 - mx);
    float sum = e0 + e1 + e2 + e3;
#pragma unroll
    for (int o = 1; o < 16; o <<= 1) sum += __shfl_xor(sum, o, 64);
    float inv = 1.0f / sum;
    int prow = w * 16 + q * 4 + r;
    Ps[prow * 72 + 0 * 16 + il] = f2bf(e0 * inv);
    Ps[prow * 72 + 1 * 16 + il] = f2bf(e1 * inv);
    Ps[prow * 72 + 2 * 16 + il] = f2bf(e2 * inv);
    Ps[prow * 72 + 3 * 16 + il] = f2bf(e3 * inv);
  }
  __syncthreads();

  // O = P V : A-frag from Ps rows, B-frag from Vt rows (= V columns)
  f32x4 oacc[4] = {};
#pragma unroll
  for (int ks = 0; ks < 2; ++ks) {
    bf16x8 ap = *(const bf16x8*)&Ps[(w * 16 + il) * 72 + ks * 32 + q * 8];
#pragma unroll
    for (int dt = 0; dt < 4; ++dt) {
      bf16x8 bv = *(const bf16x8*)&Vt[(dt * 16 + il) * 72 + ks * 32 + q * 8];
      oacc[dt] = __builtin_amdgcn_mfma_f32_16x16x32_bf16(ap, bv, oacc[dt], 0, 0, 0);
    }
  }

  const float* cs = cso + ((long)b * NW_ + n) * D_ + h * 64;
#pragma unroll
  for (int dt = 0; dt < 4; ++dt) {
    int col = dt * 16 + il;
    float cadd = 0.25f * cs[col];
#pragma unroll
    for (int r = 0; r < 4; ++r) {
      int row = w * 16 + q * 4 + r;
      qkv[(rowbase + row) * 3072 + h * 64 + col] = f2bf(oacc[dt][r] + cadd);
    }
  }
}

extern "C" void kernel_launch(void* const* d_in, const int* in_sizes, int n_in,
                              void* d_out, int out_size, void* d_ws, size_t ws_size,
                              hipStream_t stream)
{
  (void)in_sizes; (void)n_in; (void)out_size; (void)ws_size;
  const float* x      = (const float*)d_in[0];
  const float* Wqkv   = (const float*)d_in[1];
  const float* Wout   = (const float*)d_in[2];
  const float* bout   = (const float*)d_in[3];
  const float* Wcross = (const float*)d_in[4];
  const float* bcross = (const float*)d_in[5];
  const int*   jitter = (const int*)d_in[6];
  float* out = (float*)d_out;

  // ws layout (bytes), total 144,769,024 (same footprint as passing round 3):
  char* ws = (char*)d_ws;
  u16*   qkv    = (u16*)ws;                        // 100,663,296 (y bf16 aliases @0)
  u16*   y      = (u16*)ws;
  u16*   xb     = (u16*)(ws + 100663296);          // 33,554,432
  u16*   wqkvb  = (u16*)(ws + 134217728);          //  6,291,456
  u16*   wtmp   = (u16*)(ws + 140509184);          //  2,097,152 (Wcross, then Wout)
  float* scores = (float*)(ws + 142606336);        //     65,536
  float* summ   = (float*)(ws + 142671872);        //  1,048,576
  float* cso    = (float*)(ws + 143720448);        //  1,048,576

  dim3 blk(256);
  // fused input casts: x->xb, Wqkv->wqkvb, Wcross->wtmp
  cvt3_k<<<20480, blk, 0, stream>>>(x, xb, Wqkv, wqkvb, Wcross, wtmp);
  // cross-score path
  gemm_bt<<<dim3(8, 128), blk, 0, stream>>>(xb, wtmp, y, nullptr, bcross, 16384, 1024, 1024, 1024);
  cvt_k<<<1024, blk, 0, stream>>>(Wout, wtmp, 1048576L);   // wtmp free after cross gemm
  scores_k<<<4096, blk, 0, stream>>>(y, scores);
  summar_k<<<256, blk, 0, stream>>>(x, scores, summ);
  cross_k<<<256, blk, 0, stream>>>(summ, jitter, cso);
  // main path (y dead now; qkv overwrites it)
  gemm_bt<<<dim3(24, 128), blk, 0, stream>>>(xb, wqkvb, qkv, nullptr, nullptr, 16384, 3072, 1024, 1024);
  attn_win<<<4096, blk, 0, stream>>>(qkv, cso);            // in-place -> q-slice
  gemm_bt<<<dim3(8, 128), blk, 0, stream>>>(qkv, wtmp, nullptr, out, bout, 16384, 1024, 1024, 3072);
}